// Round 14
// baseline (111.969 us; speedup 1.0000x reference)
//
#include <hip/hip_runtime.h>
#include <hip/hip_bf16.h>
#include <math.h>

// ---------------- problem constants ----------------
#define NB 4          // batch
#define LQ 1000       // queries
#define NHEAD 8
#define DHEAD 32
#define DMODEL 256
#define PSUM 64       // points per head (4 levels x 16)
#define STOT 19822    // total spatial size
#define IMGF 976.0f
#define GK 256        // K dim of all GEMMs

__device__ __constant__ int c_LH[4] = {122, 61, 31, 16};
__device__ __constant__ int c_LW[4] = {122, 61, 31, 16};
__device__ __constant__ int c_LST[4] = {0, 14884, 18605, 19566};

typedef __attribute__((ext_vector_type(8))) short bf16x8;
typedef __attribute__((ext_vector_type(4))) float f32x4;

__device__ inline unsigned int pk2(float a, float b) {
    unsigned short ua = __bfloat16_as_ushort(__float2bfloat16(a));
    unsigned short ub = __bfloat16_as_ushort(__float2bfloat16(b));
    return (unsigned int)ua | ((unsigned int)ub << 16);
}
__device__ inline float bf2f(unsigned short u) {
    return __uint_as_float(((unsigned int)u) << 16);
}
__device__ inline bf16x8 cvt8(float4 u, float4 v) {
    union { unsigned int w[4]; bf16x8 h; } r;
    r.w[0] = pk2(u.x, u.y); r.w[1] = pk2(u.z, u.w);
    r.w[2] = pk2(v.x, v.y); r.w[3] = pk2(v.z, v.w);
    return r.h;
}
__device__ inline void gll16(const void* g, void* l) {
    __builtin_amdgcn_global_load_lds(
        (const __attribute__((address_space(1))) void*)g,
        (__attribute__((address_space(3))) void*)l, 16, 0, 0);
}
// airtight barrier: nothing (incl. LDS ops / gll issues) crosses in either direction
__device__ inline void hard_barrier() {
    asm volatile("" ::: "memory");
    __builtin_amdgcn_sched_barrier(0);
    __builtin_amdgcn_s_barrier();
    __builtin_amdgcn_sched_barrier(0);
    asm volatile("" ::: "memory");
}

// ---------------- consts helper (device) ----------------
__device__ inline void make_consts(int n, const float* p_pfws, const float* pt,
                                   float* consts) {
    const float* P1 = p_pfws + n * 12;
    const float* P2 = p_pfws + (n ^ 1) * 12;
    const float* T  = pt + n * 6;
    const float* T2 = pt + (n ^ 1) * 6;
    float* C = consts + n * 48;
    float det = T[0]*T[4] - T[1]*T[3];
    float idet = 1.0f/det;
    C[0] =  T[4]*idet; C[1] = -T[1]*idet;
    C[2] = -T[3]*idet; C[3] =  T[0]*idet;
    C[4] = T[2]; C[5] = T[5];
    float a=P1[0], b=P1[1], c=P1[2];
    float d=P1[4], e=P1[5], f=P1[6];
    float g=P1[8], h=P1[9], i=P1[10];
    float b10=P1[3], b11=P1[7], b12=P1[11];
    float A_=e*i-f*h, B_=c*h-b*i, Cc=b*f-c*e;
    float D_=f*g-d*i, E_=a*i-c*g, F_=c*d-a*f;
    float G_=d*h-e*g, H_=b*g-a*h, I_=a*e-b*d;
    float det3 = a*A_ + b*D_ + c*G_;
    float id3 = 1.0f/det3;
    C[6]=A_*id3;  C[7]=B_*id3;  C[8]=Cc*id3;
    C[9]=D_*id3;  C[10]=E_*id3; C[11]=F_*id3;
    C[12]=G_*id3; C[13]=H_*id3; C[14]=I_*id3;
    C[15]=b10; C[16]=b11; C[17]=b12;
    for (int k = 0; k < 12; ++k) C[18+k] = P2[k];
    float cam0 = -(C[6]*b10  + C[7]*b11  + C[8]*b12);
    float cam1 = -(C[9]*b10  + C[10]*b11 + C[11]*b12);
    float cam2 = -(C[12]*b10 + C[13]*b11 + C[14]*b12);
    float y0 = P2[0]*cam0 + P2[1]*cam1 + P2[2]*cam2  + P2[3];
    float y1 = P2[4]*cam0 + P2[5]*cam1 + P2[6]*cam2  + P2[7];
    float y2 = P2[8]*cam0 + P2[9]*cam1 + P2[10]*cam2 + P2[11];
    float inv = 1.0f/(y2 + 1e-8f);
    C[30] = y0*inv; C[31] = y1*inv;
    for (int k = 0; k < 6; ++k) C[32+k] = T2[k];
}

// ---------------- prep: convert 3 weights to bf16 + setup consts ----------------
__global__ void prep(const float* __restrict__ Wv, const float* __restrict__ Wa,
                     const float* __restrict__ Wo,
                     unsigned short* __restrict__ wbv, unsigned short* __restrict__ wba,
                     unsigned short* __restrict__ wbo,
                     const float* __restrict__ p_pfws, const float* __restrict__ pt,
                     float* __restrict__ consts) {
    int bid = blockIdx.x;
    if (bid == 256) {
        int n = threadIdx.x;
        if (n < NB) make_consts(n, p_pfws, pt, consts);
        return;
    }
    int i = bid * 256 + threadIdx.x;          // float4 index
    const float* src; unsigned short* dst; int off;
    if (i < 16384)      { src = Wv; dst = wbv; off = i; }
    else if (i < 49152) { src = Wa; dst = wba; off = i - 16384; }
    else                { src = Wo; dst = wbo; off = i - 49152; }
    float4 f = ((const float4*)src)[off];
    ushort4 o;
    o.x = __bfloat16_as_ushort(__float2bfloat16(f.x));
    o.y = __bfloat16_as_ushort(__float2bfloat16(f.y));
    o.z = __bfloat16_as_ushort(__float2bfloat16(f.z));
    o.w = __bfloat16_as_ushort(__float2bfloat16(f.w));
    ((ushort4*)dst)[off] = o;
}

// ---------------- value GEMM: reg-B + gll-A rows pipeline (R12-proven) ----------------
// launch_bounds(256,1): occupancy is LDS-capped at 2 blocks/CU anyway; freeing the
// VGPR budget lets the allocator keep the 128-reg B panel resident (R12: gemm_val
// dropped out of top-5, ~31-35us inferred).
__global__ __launch_bounds__(256, 1)
void gemm_val_regB(const float* __restrict__ X, const unsigned short* __restrict__ Wb,
                   const float* __restrict__ bias, unsigned short* __restrict__ out,
                   int M, int T, int CHUNK) {
    __shared__ __align__(16) char As[2][32768];   // fp32 [32 rows][256 k] swizzled
    const int tid  = threadIdx.x;
    const int lane = tid & 63;
    const int wq   = tid >> 6;            // wave = col quarter
    const int l15  = lane & 15;
    const int koct = lane >> 4;           // 0..3
    const int t0   = blockIdx.x * CHUNK;
    int nt = T - t0; if (nt > CHUNK) nt = CHUNK;
    if (nt <= 0) return;

    // ---- B panel into registers (loaded once) ----
    bf16x8 breg[8][4];
    #pragma unroll
    for (int ks = 0; ks < 8; ++ks)
        #pragma unroll
        for (int ni = 0; ni < 4; ++ni) {
            int col = wq * 64 + ni * 16 + l15;
            breg[ks][ni] = *(const bf16x8*)((const char*)Wb + (size_t)col * 512
                                            + ks * 64 + koct * 16);
        }
    float bias_v[4];
    #pragma unroll
    for (int ni = 0; ni < 4; ++ni) bias_v[ni] = bias[wq * 64 + ni * 16 + l15];

#define STAGE(g, b) do {                                                      \
        _Pragma("unroll") for (int j = 0; j < 8; ++j) {                       \
            int r_ = wq * 8 + j;                                              \
            int gr_ = (g) * 32 + r_; if (gr_ >= M) gr_ = M - 1;               \
            int lch_ = lane ^ (r_ & 7);                                       \
            gll16(X + (size_t)gr_ * GK + lch_ * 4, As[b] + r_ * 1024);        \
        } } while (0)

    STAGE(t0, 0);
    if (nt > 1) { STAGE(t0 + 1, 1); asm volatile("s_waitcnt vmcnt(8)" ::: "memory"); }
    else        {                   asm volatile("s_waitcnt vmcnt(0)" ::: "memory"); }
    hard_barrier();

#define COMPUTE_STORE(g, b) do {                                              \
        f32x4 acc[2][4] = {};                                                 \
        _Pragma("unroll") for (int ks = 0; ks < 8; ++ks) {                    \
            _Pragma("unroll") for (int mi = 0; mi < 2; ++mi) {                \
                int r_ = mi * 16 + l15;                                       \
                int ch_ = ks * 8 + koct * 2;                                  \
                float4 x0_ = *(const float4*)(As[b] + r_ * 1024 +             \
                                              ((ch_    ) ^ (r_ & 7)) * 16);   \
                float4 x1_ = *(const float4*)(As[b] + r_ * 1024 +             \
                                              ((ch_ + 1) ^ (r_ & 7)) * 16);   \
                bf16x8 af_ = cvt8(x0_, x1_);                                  \
                _Pragma("unroll") for (int ni = 0; ni < 4; ++ni)              \
                    acc[mi][ni] = __builtin_amdgcn_mfma_f32_16x16x32_bf16(    \
                        af_, breg[ks][ni], acc[mi][ni], 0, 0, 0);             \
            }                                                                 \
        }                                                                     \
        _Pragma("unroll") for (int mi = 0; mi < 2; ++mi) {                    \
            int rb_ = (g) * 32 + mi * 16 + (lane >> 4) * 4;                   \
            _Pragma("unroll") for (int j_ = 0; j_ < 4; ++j_) {                \
                int gr_ = rb_ + j_;                                           \
                if (gr_ < M) {                                                \
                    _Pragma("unroll") for (int ni = 0; ni < 4; ++ni)          \
                        out[(size_t)gr_ * DMODEL + wq * 64 + ni * 16 + l15] = \
                            __bfloat16_as_ushort(__float2bfloat16(            \
                                acc[mi][ni][j_] + bias_v[ni]));               \
                }                                                             \
            }                                                                 \
        } } while (0)

    for (int t = 0; t < nt; ++t) {
        COMPUTE_STORE(t0 + t, t & 1);
        if (t + 1 == nt) break;
        hard_barrier();                        // all waves done reading As[t&1]
        if (t + 2 < nt) {
            STAGE(t0 + t + 2, t & 1);          // refill freed buffer (global tile)
            // age order: [S(t-1)]32, G(t+1)8, S(t)32, G(t+2)8 -> retire thru G(t+1)
            asm volatile("s_waitcnt vmcnt(40)" ::: "memory");
        } else {
            asm volatile("s_waitcnt vmcnt(32)" ::: "memory");   // tail
        }
        hard_barrier();                        // tile t+1 visible to all waves
    }
#undef COMPUTE_STORE
#undef STAGE
}

// ---------------- small GEMMs (logits, out): proven gemm64 ----------------
template<bool OUT_BF16>
__global__ __launch_bounds__(256, 4)
void gemm64(const float* __restrict__ A, const unsigned short* __restrict__ Bb,
            const float* __restrict__ bias, void* __restrict__ outp,
            int M, int N) {
    __shared__ char smem[40960];
    char* asmem = smem;
    char* bsmem = smem + 8192;
    const int tid  = threadIdx.x;
    const int lane = tid & 63;
    const int w    = tid >> 6;
    const int l15  = lane & 15;
    const int koct = lane >> 4;
    const int i0 = blockIdx.x * 64;
    const int o0 = blockIdx.y * 256;

    const int s_row = tid >> 2;
    const int s_q   = tid & 3;
    int gr = i0 + s_row; gr = gr < M ? gr : M - 1;
    const float* aptr = A + (size_t)gr * GK + s_q * 16;
    const int s_sw = (s_row & 7) << 4;
    char* a_w0 = asmem + s_row * 128 + ((s_q * 32)      ^ s_sw);
    char* a_w1 = asmem + s_row * 128 + ((s_q * 32 + 16) ^ s_sw);

    const int b_sub = lane >> 3;
    const int b_kc  = (lane & 7) ^ b_sub;

    f32x4 acc[4][4] = {};
    float bias_v[4];
    #pragma unroll
    for (int ni = 0; ni < 4; ++ni) bias_v[ni] = bias[o0 + w * 64 + ni * 16 + l15];

    for (int t = 0; t < 4; ++t) {
        const int k0 = t * 64;
        #pragma unroll
        for (int j = 0; j < 8; ++j) {
            int cI = w * 8 + j;
            int col = cI * 8 + b_sub;
            gll16(Bb + (size_t)(o0 + col) * GK + k0 + b_kc * 8,
                  bsmem + cI * 1024);
        }
        {
            const float4* s = (const float4*)(aptr + k0);
            float4 f0 = s[0], f1 = s[1], f2 = s[2], f3 = s[3];
            uint4 wv0, wv1;
            wv0.x = pk2(f0.x,f0.y); wv0.y = pk2(f0.z,f0.w);
            wv0.z = pk2(f1.x,f1.y); wv0.w = pk2(f1.z,f1.w);
            wv1.x = pk2(f2.x,f2.y); wv1.y = pk2(f2.z,f2.w);
            wv1.z = pk2(f3.x,f3.y); wv1.w = pk2(f3.z,f3.w);
            *(uint4*)a_w0 = wv0;
            *(uint4*)a_w1 = wv1;
        }
        __syncthreads();
        #pragma unroll
        for (int ks = 0; ks < 2; ++ks) {
            const int kc = ks * 4 + koct;
            bf16x8 af[4], bfr[4];
            #pragma unroll
            for (int mi = 0; mi < 4; ++mi) {
                int r = mi * 16 + l15;
                af[mi] = *(const bf16x8*)(asmem + r * 128 + ((kc * 16) ^ ((r & 7) << 4)));
            }
            #pragma unroll
            for (int ni = 0; ni < 4; ++ni) {
                int c = w * 64 + ni * 16 + l15;
                bfr[ni] = *(const bf16x8*)(bsmem + c * 128 + ((kc * 16) ^ ((c & 7) << 4)));
            }
            #pragma unroll
            for (int mi = 0; mi < 4; ++mi)
                #pragma unroll
                for (int ni = 0; ni < 4; ++ni)
                    acc[mi][ni] = __builtin_amdgcn_mfma_f32_16x16x32_bf16(
                        af[mi], bfr[ni], acc[mi][ni], 0, 0, 0);
        }
        __syncthreads();
    }

    #pragma unroll
    for (int mi = 0; mi < 4; ++mi) {
        int rbase = i0 + mi * 16 + (lane >> 4) * 4;
        #pragma unroll
        for (int j = 0; j < 4; ++j) {
            int grow = rbase + j;
            if (grow < M) {
                #pragma unroll
                for (int ni = 0; ni < 4; ++ni) {
                    int gcol = o0 + w * 64 + ni * 16 + l15;
                    float v = acc[mi][ni][j] + bias_v[ni];
                    if (OUT_BF16)
                        ((unsigned short*)outp)[(size_t)grow * N + gcol] =
                            __bfloat16_as_ushort(__float2bfloat16(v));
                    else
                        ((float*)outp)[(size_t)grow * N + gcol] = v;
                }
            }
        }
    }
}

// ---------------- fused: softmax + locations + gather (512 thr, short chains) ----------------
// R13 evidence: 16-iter dependent-gather chain + branchy loads = latency-bound
// (VALUBusy 25%, VGPR 36). Restructure: 8 waves; wave w owns 8 points; each
// HALF-WAVE processes one point per iteration (lane: bf16x8 = 16B = 8 channels,
// half-wave = full 512B row). 4 iterations x 8 independent unconditional loads
// (zero-weight clamped corners - no branch on the load path). Halves merged with
// 8 shfl_xor(32); padded s_part[8][32][9] partial reduce.
__global__ __launch_bounds__(512)
void fused_sample(const float* __restrict__ logits,        // (4000, 512) m*64+p
                  const float* __restrict__ ref_pts,       // (4,1000,2)
                  const unsigned short* __restrict__ value,// bf16 (4, 19822, 256)
                  const float* __restrict__ consts,        // 4*48
                  float* __restrict__ attn_out) {          // (4000, 256)
    int b = blockIdx.x;
    int n = b / LQ;
    int q = b - n * LQ;
    int tid = threadIdx.x;

    __shared__ float s_attn[512];
    __shared__ float s_loc[16][2];
    __shared__ int   s_idx[64][4];
    __shared__ float s_w[64][4];
    __shared__ float s_part[8][32][9];

    s_attn[tid] = logits[(size_t)b * 512 + tid];
    __syncthreads();

    {   // softmax: one head per wave (8 waves = 8 heads), lane = point
        int wave = tid >> 6, lane = tid & 63;
        float v = s_attn[wave * 64 + lane];
        float mx = v;
        #pragma unroll
        for (int off = 32; off; off >>= 1) mx = fmaxf(mx, __shfl_xor(mx, off, 64));
        float e = expf(v - mx);
        float sm = e;
        #pragma unroll
        for (int off = 32; off; off >>= 1) sm += __shfl_xor(sm, off, 64);
        __syncthreads();               // all reads of raw logits done
        s_attn[wave * 64 + lane] = e / sm;
    }

    if (tid < 16) {   // 16 distinct sampling locations (shared by all 4 levels)
        const float* C = consts + n * 48;
        float rx = ref_pts[((size_t)n * LQ + q) * 2 + 0];
        float ry = ref_pts[((size_t)n * LQ + q) * 2 + 1];
        float dx = rx - C[4], dy = ry - C[5];
        float ox = (C[0]*dx + C[1]*dy) * IMGF;
        float oy = (C[2]*dx + C[3]*dy) * IMGF;
        float u0 = ox - C[15], u1 = oy - C[16], u2 = 1.0f - C[17];
        float r0 = C[6]*u0  + C[7]*u1  + C[8]*u2;
        float r1 = C[9]*u0  + C[10]*u1 + C[11]*u2;
        float r2 = C[12]*u0 + C[13]*u1 + C[14]*u2;
        float y0 = C[18]*r0 + C[19]*r1 + C[20]*r2 + C[21];
        float y1 = C[22]*r0 + C[23]*r1 + C[24]*r2 + C[25];
        float y2 = C[26]*r0 + C[27]*r1 + C[28]*r2 + C[29];
        float inv = 1.0f/(y2 + 1e-8f);
        float prx = y0*inv, pry = y1*inv;
        float ts0 = C[30], ts1 = C[31];
        float msx = (prx - ts0) / IMGF, msy = (pry - ts1) / IMGF;
        int j = tid;
        float xsj = IMGF * ((float)j / 15.0f);
        float lx = (ts0 + msx * xsj) / IMGF;
        float ly = (ts1 + msy * xsj) / IMGF;
        float Lx = C[32]*lx + C[33]*ly + C[34];
        float Ly = C[35]*lx + C[36]*ly + C[37];
        s_loc[j][0] = fminf(fmaxf(Lx, 0.0f), 1.0f);
        s_loc[j][1] = fminf(fmaxf(Ly, 0.0f), 1.0f);
    }
    __syncthreads();

    if (tid < 64) {   // bilinear metadata: CLAMPED indices + zero weights (no branches later)
        int p = tid, lev = p >> 4, j = p & 15;
        int H = c_LH[lev], W = c_LW[lev], st = c_LST[lev];
        float gx = s_loc[j][0] * (float)W - 0.5f;
        float gy = s_loc[j][1] * (float)H - 0.5f;
        float x0f = floorf(gx), y0f = floorf(gy);
        float wx = gx - x0f, wy = gy - y0f;
        int x0 = (int)x0f, y0 = (int)y0f;
        int x1 = x0 + 1, y1 = y0 + 1;
        bool vx0 = (x0 >= 0) & (x0 < W), vx1 = (x1 >= 0) & (x1 < W);
        bool vy0 = (y0 >= 0) & (y0 < H), vy1 = (y1 >= 0) & (y1 < H);
        int x0c = min(max(x0, 0), W - 1), x1c = min(max(x1, 0), W - 1);
        int y0c = min(max(y0, 0), H - 1), y1c = min(max(y1, 0), H - 1);
        s_idx[p][0] = st + y0c * W + x0c;  s_w[p][0] = (vx0 & vy0) ? (1.f-wx)*(1.f-wy) : 0.f;
        s_idx[p][1] = st + y0c * W + x1c;  s_w[p][1] = (vx1 & vy0) ? wx*(1.f-wy)       : 0.f;
        s_idx[p][2] = st + y1c * W + x0c;  s_w[p][2] = (vx0 & vy1) ? (1.f-wx)*wy       : 0.f;
        s_idx[p][3] = st + y1c * W + x1c;  s_w[p][3] = (vx1 & vy1) ? wx*wy             : 0.f;
    }
    __syncthreads();

    // gather: wave wv -> points wv*8..+7; half-wave per point; lane: 8 channels (16B)
    int wv = tid >> 6, lane = tid & 63;
    int half = lane >> 5, l31 = lane & 31;
    const unsigned short* valb = value + (size_t)(n ^ 1) * STOT * DMODEL + l31 * 8;
    int m = l31 >> 2;   // head of channels l31*8..+7
    float a0=0.f,a1=0.f,a2=0.f,a3=0.f,a4=0.f,a5=0.f,a6=0.f,a7=0.f;
    #pragma unroll
    for (int j = 0; j < 4; ++j) {
        int p = wv * 8 + j * 2 + half;
        float wa = s_attn[m * 64 + p];
        bf16x8 v0 = *(const bf16x8*)(valb + (size_t)s_idx[p][0] * DMODEL);
        bf16x8 v1 = *(const bf16x8*)(valb + (size_t)s_idx[p][1] * DMODEL);
        bf16x8 v2 = *(const bf16x8*)(valb + (size_t)s_idx[p][2] * DMODEL);
        bf16x8 v3 = *(const bf16x8*)(valb + (size_t)s_idx[p][3] * DMODEL);
        float w0 = s_w[p][0], w1 = s_w[p][1], w2 = s_w[p][2], w3 = s_w[p][3];
        #pragma unroll
        for (int e = 0; e < 8; ++e) {
            float s = w0 * bf2f((unsigned short)v0[e]) + w1 * bf2f((unsigned short)v1[e])
                    + w2 * bf2f((unsigned short)v2[e]) + w3 * bf2f((unsigned short)v3[e]);
            float ws = wa * s;
            switch (e) {
                case 0: a0 += ws; break; case 1: a1 += ws; break;
                case 2: a2 += ws; break; case 3: a3 += ws; break;
                case 4: a4 += ws; break; case 5: a5 += ws; break;
                case 6: a6 += ws; break; case 7: a7 += ws; break;
            }
        }
    }
    // merge the two halves (different points, same channels): 8 shuffles
    a0 += __shfl_xor(a0, 32, 64);  a1 += __shfl_xor(a1, 32, 64);
    a2 += __shfl_xor(a2, 32, 64);  a3 += __shfl_xor(a3, 32, 64);
    a4 += __shfl_xor(a4, 32, 64);  a5 += __shfl_xor(a5, 32, 64);
    a6 += __shfl_xor(a6, 32, 64);  a7 += __shfl_xor(a7, 32, 64);
    if (half == 0) {
        s_part[wv][l31][0] = a0; s_part[wv][l31][1] = a1;
        s_part[wv][l31][2] = a2; s_part[wv][l31][3] = a3;
        s_part[wv][l31][4] = a4; s_part[wv][l31][5] = a5;
        s_part[wv][l31][6] = a6; s_part[wv][l31][7] = a7;
    }
    __syncthreads();

    if (tid < DMODEL) {
        int cg = tid >> 3, ce = tid & 7;
        float r = s_part[0][cg][ce] + s_part[1][cg][ce]
                + s_part[2][cg][ce] + s_part[3][cg][ce]
                + s_part[4][cg][ce] + s_part[5][cg][ce]
                + s_part[6][cg][ce] + s_part[7][cg][ce];
        attn_out[(size_t)b * DMODEL + tid] = r;
    }
}

// ---------------- launch ----------------
extern "C" void kernel_launch(void* const* d_in, const int* in_sizes, int n_in,
                              void* d_out, int out_size, void* d_ws, size_t ws_size,
                              hipStream_t stream) {
    const float* query         = (const float*)d_in[0];
    const float* input_flatten = (const float*)d_in[1];
    const float* ref_pts       = (const float*)d_in[2];
    const float* p_pfws        = (const float*)d_in[3];
    const float* pt            = (const float*)d_in[4];
    const float* W_val         = (const float*)d_in[5];
    const float* b_val         = (const float*)d_in[6];
    const float* W_attn        = (const float*)d_in[7];
    const float* b_attn        = (const float*)d_in[8];
    const float* W_out         = (const float*)d_in[9];
    const float* b_out         = (const float*)d_in[10];
    float* out = (float*)d_out;

    const int M = NB * STOT;                                   // 79288
    const size_t value_bytes  = (size_t)M * DMODEL * 2;        // bf16
    const size_t logits_bytes = (size_t)NB * LQ * 512 * 4;
    const size_t attn_bytes   = (size_t)NB * LQ * DMODEL * 4;
    const size_t consts_bytes = NB * 48 * 4;
    const size_t wv_bytes     = (size_t)DMODEL * DMODEL * 2;
    const size_t wa_bytes     = (size_t)512 * DMODEL * 2;
    const size_t wo_bytes     = (size_t)DMODEL * DMODEL * 2;
    const size_t need = value_bytes + logits_bytes + attn_bytes + consts_bytes
                      + wv_bytes + wa_bytes + wo_bytes;
    if (ws_size < need) return;

    char* p = (char*)d_ws;
    unsigned short* value = (unsigned short*)p;  p += value_bytes;
    float* logits   = (float*)p;                 p += logits_bytes;
    float* attn_out = (float*)p;                 p += attn_bytes;
    float* consts   = (float*)p;                 p += consts_bytes;
    unsigned short* wb_val  = (unsigned short*)p; p += wv_bytes;
    unsigned short* wb_attn = (unsigned short*)p; p += wa_bytes;
    unsigned short* wb_out  = (unsigned short*)p; p += wo_bytes;

    prep<<<257, 256, 0, stream>>>(W_val, W_attn, W_out, wb_val, wb_attn, wb_out,
                                  p_pfws, pt, consts);

    {   // value = bf16(input_flatten @ W_val.T + b_val): reg-B rows pipeline
        const int T = (M + 31) / 32;               // 2478 row tiles
        const int CHUNK = 5;
        const int blocks = (T + CHUNK - 1) / CHUNK; // 496
        gemm_val_regB<<<blocks, 256, 0, stream>>>(input_flatten, wb_val, b_val,
                                                  value, M, T, CHUNK);
    }
    {   // logits = query @ W_attn.T + b_attn   (N=512 -> grid.y=2)
        dim3 g((NB * LQ + 63) / 64, 2);
        gemm64<false><<<g, 256, 0, stream>>>(query, wb_attn, b_attn, logits, NB * LQ, 512);
    }
    fused_sample<<<NB * LQ, 512, 0, stream>>>(logits, ref_pts, value, consts, attn_out);
    {   // out = attn_out @ W_out.T + b_out
        dim3 g((NB * LQ + 63) / 64, 1);
        gemm64<false><<<g, 256, 0, stream>>>(attn_out, wb_out, b_out, out, NB * LQ, DMODEL);
    }
}

// Round 15
// 93.999 us; speedup vs baseline: 1.1912x; 1.1912x over previous
//
#include <hip/hip_runtime.h>
#include <hip/hip_bf16.h>
#include <math.h>

// ---------------- problem constants ----------------
#define NB 4          // batch
#define LQ 1000       // queries
#define NHEAD 8
#define DHEAD 32
#define DMODEL 256
#define PSUM 64       // points per head (4 levels x 16)
#define STOT 19822    // total spatial size
#define IMGF 976.0f
#define GK 256        // K dim of all GEMMs

__device__ __constant__ int c_LH[4] = {122, 61, 31, 16};
__device__ __constant__ int c_LW[4] = {122, 61, 31, 16};
__device__ __constant__ int c_LST[4] = {0, 14884, 18605, 19566};

typedef __attribute__((ext_vector_type(8))) short bf16x8;
typedef __attribute__((ext_vector_type(4))) float f32x4;

__device__ inline unsigned int pk2(float a, float b) {
    unsigned short ua = __bfloat16_as_ushort(__float2bfloat16(a));
    unsigned short ub = __bfloat16_as_ushort(__float2bfloat16(b));
    return (unsigned int)ua | ((unsigned int)ub << 16);
}
__device__ inline float bf2f(unsigned short u) {
    return __uint_as_float(((unsigned int)u) << 16);
}
__device__ inline bf16x8 cvt8(float4 u, float4 v) {
    union { unsigned int w[4]; bf16x8 h; } r;
    r.w[0] = pk2(u.x, u.y); r.w[1] = pk2(u.z, u.w);
    r.w[2] = pk2(v.x, v.y); r.w[3] = pk2(v.z, v.w);
    return r.h;
}
__device__ inline void gll16(const void* g, void* l) {
    __builtin_amdgcn_global_load_lds(
        (const __attribute__((address_space(1))) void*)g,
        (__attribute__((address_space(3))) void*)l, 16, 0, 0);
}
// airtight barrier: nothing (incl. LDS ops / gll issues) crosses in either direction
__device__ inline void hard_barrier() {
    asm volatile("" ::: "memory");
    __builtin_amdgcn_sched_barrier(0);
    __builtin_amdgcn_s_barrier();
    __builtin_amdgcn_sched_barrier(0);
    asm volatile("" ::: "memory");
}

// ---------------- consts helper (device) ----------------
__device__ inline void make_consts(int n, const float* p_pfws, const float* pt,
                                   float* consts) {
    const float* P1 = p_pfws + n * 12;
    const float* P2 = p_pfws + (n ^ 1) * 12;
    const float* T  = pt + n * 6;
    const float* T2 = pt + (n ^ 1) * 6;
    float* C = consts + n * 48;
    float det = T[0]*T[4] - T[1]*T[3];
    float idet = 1.0f/det;
    C[0] =  T[4]*idet; C[1] = -T[1]*idet;
    C[2] = -T[3]*idet; C[3] =  T[0]*idet;
    C[4] = T[2]; C[5] = T[5];
    float a=P1[0], b=P1[1], c=P1[2];
    float d=P1[4], e=P1[5], f=P1[6];
    float g=P1[8], h=P1[9], i=P1[10];
    float b10=P1[3], b11=P1[7], b12=P1[11];
    float A_=e*i-f*h, B_=c*h-b*i, Cc=b*f-c*e;
    float D_=f*g-d*i, E_=a*i-c*g, F_=c*d-a*f;
    float G_=d*h-e*g, H_=b*g-a*h, I_=a*e-b*d;
    float det3 = a*A_ + b*D_ + c*G_;
    float id3 = 1.0f/det3;
    C[6]=A_*id3;  C[7]=B_*id3;  C[8]=Cc*id3;
    C[9]=D_*id3;  C[10]=E_*id3; C[11]=F_*id3;
    C[12]=G_*id3; C[13]=H_*id3; C[14]=I_*id3;
    C[15]=b10; C[16]=b11; C[17]=b12;
    for (int k = 0; k < 12; ++k) C[18+k] = P2[k];
    float cam0 = -(C[6]*b10  + C[7]*b11  + C[8]*b12);
    float cam1 = -(C[9]*b10  + C[10]*b11 + C[11]*b12);
    float cam2 = -(C[12]*b10 + C[13]*b11 + C[14]*b12);
    float y0 = P2[0]*cam0 + P2[1]*cam1 + P2[2]*cam2  + P2[3];
    float y1 = P2[4]*cam0 + P2[5]*cam1 + P2[6]*cam2  + P2[7];
    float y2 = P2[8]*cam0 + P2[9]*cam1 + P2[10]*cam2 + P2[11];
    float inv = 1.0f/(y2 + 1e-8f);
    C[30] = y0*inv; C[31] = y1*inv;
    for (int k = 0; k < 6; ++k) C[32+k] = T2[k];
}

// ---------------- prep: convert 3 weights to bf16 + setup consts ----------------
__global__ void prep(const float* __restrict__ Wv, const float* __restrict__ Wa,
                     const float* __restrict__ Wo,
                     unsigned short* __restrict__ wbv, unsigned short* __restrict__ wba,
                     unsigned short* __restrict__ wbo,
                     const float* __restrict__ p_pfws, const float* __restrict__ pt,
                     float* __restrict__ consts) {
    int bid = blockIdx.x;
    if (bid == 256) {
        int n = threadIdx.x;
        if (n < NB) make_consts(n, p_pfws, pt, consts);
        return;
    }
    int i = bid * 256 + threadIdx.x;          // float4 index
    const float* src; unsigned short* dst; int off;
    if (i < 16384)      { src = Wv; dst = wbv; off = i; }
    else if (i < 49152) { src = Wa; dst = wba; off = i - 16384; }
    else                { src = Wo; dst = wbo; off = i - 49152; }
    float4 f = ((const float4*)src)[off];
    ushort4 o;
    o.x = __bfloat16_as_ushort(__float2bfloat16(f.x));
    o.y = __bfloat16_as_ushort(__float2bfloat16(f.y));
    o.z = __bfloat16_as_ushort(__float2bfloat16(f.z));
    o.w = __bfloat16_as_ushort(__float2bfloat16(f.w));
    ((ushort4*)dst)[off] = o;
}

// ---------------- value GEMM: reg-B + gll-A rows pipeline (R12-proven) ----------------
// launch_bounds(256,1): occupancy is LDS-capped at 2 blocks/CU anyway; freeing the
// VGPR budget lets the allocator keep the 128-reg B panel resident (R12: gemm_val
// dropped out of top-5, ~31-35us inferred vs 49-52 at launch_bounds(256,2)).
__global__ __launch_bounds__(256, 1)
void gemm_val_regB(const float* __restrict__ X, const unsigned short* __restrict__ Wb,
                   const float* __restrict__ bias, unsigned short* __restrict__ out,
                   int M, int T, int CHUNK) {
    __shared__ __align__(16) char As[2][32768];   // fp32 [32 rows][256 k] swizzled
    const int tid  = threadIdx.x;
    const int lane = tid & 63;
    const int wq   = tid >> 6;            // wave = col quarter
    const int l15  = lane & 15;
    const int koct = lane >> 4;           // 0..3
    const int t0   = blockIdx.x * CHUNK;
    int nt = T - t0; if (nt > CHUNK) nt = CHUNK;
    if (nt <= 0) return;

    // ---- B panel into registers (loaded once) ----
    bf16x8 breg[8][4];
    #pragma unroll
    for (int ks = 0; ks < 8; ++ks)
        #pragma unroll
        for (int ni = 0; ni < 4; ++ni) {
            int col = wq * 64 + ni * 16 + l15;
            breg[ks][ni] = *(const bf16x8*)((const char*)Wb + (size_t)col * 512
                                            + ks * 64 + koct * 16);
        }
    float bias_v[4];
    #pragma unroll
    for (int ni = 0; ni < 4; ++ni) bias_v[ni] = bias[wq * 64 + ni * 16 + l15];

#define STAGE(g, b) do {                                                      \
        _Pragma("unroll") for (int j = 0; j < 8; ++j) {                       \
            int r_ = wq * 8 + j;                                              \
            int gr_ = (g) * 32 + r_; if (gr_ >= M) gr_ = M - 1;               \
            int lch_ = lane ^ (r_ & 7);                                       \
            gll16(X + (size_t)gr_ * GK + lch_ * 4, As[b] + r_ * 1024);        \
        } } while (0)

    STAGE(t0, 0);
    if (nt > 1) { STAGE(t0 + 1, 1); asm volatile("s_waitcnt vmcnt(8)" ::: "memory"); }
    else        {                   asm volatile("s_waitcnt vmcnt(0)" ::: "memory"); }
    hard_barrier();

#define COMPUTE_STORE(g, b) do {                                              \
        f32x4 acc[2][4] = {};                                                 \
        _Pragma("unroll") for (int ks = 0; ks < 8; ++ks) {                    \
            _Pragma("unroll") for (int mi = 0; mi < 2; ++mi) {                \
                int r_ = mi * 16 + l15;                                       \
                int ch_ = ks * 8 + koct * 2;                                  \
                float4 x0_ = *(const float4*)(As[b] + r_ * 1024 +             \
                                              ((ch_    ) ^ (r_ & 7)) * 16);   \
                float4 x1_ = *(const float4*)(As[b] + r_ * 1024 +             \
                                              ((ch_ + 1) ^ (r_ & 7)) * 16);   \
                bf16x8 af_ = cvt8(x0_, x1_);                                  \
                _Pragma("unroll") for (int ni = 0; ni < 4; ++ni)              \
                    acc[mi][ni] = __builtin_amdgcn_mfma_f32_16x16x32_bf16(    \
                        af_, breg[ks][ni], acc[mi][ni], 0, 0, 0);             \
            }                                                                 \
        }                                                                     \
        _Pragma("unroll") for (int mi = 0; mi < 2; ++mi) {                    \
            int rb_ = (g) * 32 + mi * 16 + (lane >> 4) * 4;                   \
            _Pragma("unroll") for (int j_ = 0; j_ < 4; ++j_) {                \
                int gr_ = rb_ + j_;                                           \
                if (gr_ < M) {                                                \
                    _Pragma("unroll") for (int ni = 0; ni < 4; ++ni)          \
                        out[(size_t)gr_ * DMODEL + wq * 64 + ni * 16 + l15] = \
                            __bfloat16_as_ushort(__float2bfloat16(            \
                                acc[mi][ni][j_] + bias_v[ni]));               \
                }                                                             \
            }                                                                 \
        } } while (0)

    for (int t = 0; t < nt; ++t) {
        COMPUTE_STORE(t0 + t, t & 1);
        if (t + 1 == nt) break;
        hard_barrier();                        // all waves done reading As[t&1]
        if (t + 2 < nt) {
            STAGE(t0 + t + 2, t & 1);          // refill freed buffer (global tile)
            // age order: [S(t-1)]32, G(t+1)8, S(t)32, G(t+2)8 -> retire thru G(t+1)
            asm volatile("s_waitcnt vmcnt(40)" ::: "memory");
        } else {
            asm volatile("s_waitcnt vmcnt(32)" ::: "memory");   // tail
        }
        hard_barrier();                        // tile t+1 visible to all waves
    }
#undef COMPUTE_STORE
#undef STAGE
}

// ---------------- small GEMMs (logits, out): proven gemm64 ----------------
template<bool OUT_BF16>
__global__ __launch_bounds__(256, 4)
void gemm64(const float* __restrict__ A, const unsigned short* __restrict__ Bb,
            const float* __restrict__ bias, void* __restrict__ outp,
            int M, int N) {
    __shared__ char smem[40960];
    char* asmem = smem;
    char* bsmem = smem + 8192;
    const int tid  = threadIdx.x;
    const int lane = tid & 63;
    const int w    = tid >> 6;
    const int l15  = lane & 15;
    const int koct = lane >> 4;
    const int i0 = blockIdx.x * 64;
    const int o0 = blockIdx.y * 256;

    const int s_row = tid >> 2;
    const int s_q   = tid & 3;
    int gr = i0 + s_row; gr = gr < M ? gr : M - 1;
    const float* aptr = A + (size_t)gr * GK + s_q * 16;
    const int s_sw = (s_row & 7) << 4;
    char* a_w0 = asmem + s_row * 128 + ((s_q * 32)      ^ s_sw);
    char* a_w1 = asmem + s_row * 128 + ((s_q * 32 + 16) ^ s_sw);

    const int b_sub = lane >> 3;
    const int b_kc  = (lane & 7) ^ b_sub;

    f32x4 acc[4][4] = {};
    float bias_v[4];
    #pragma unroll
    for (int ni = 0; ni < 4; ++ni) bias_v[ni] = bias[o0 + w * 64 + ni * 16 + l15];

    for (int t = 0; t < 4; ++t) {
        const int k0 = t * 64;
        #pragma unroll
        for (int j = 0; j < 8; ++j) {
            int cI = w * 8 + j;
            int col = cI * 8 + b_sub;
            gll16(Bb + (size_t)(o0 + col) * GK + k0 + b_kc * 8,
                  bsmem + cI * 1024);
        }
        {
            const float4* s = (const float4*)(aptr + k0);
            float4 f0 = s[0], f1 = s[1], f2 = s[2], f3 = s[3];
            uint4 wv0, wv1;
            wv0.x = pk2(f0.x,f0.y); wv0.y = pk2(f0.z,f0.w);
            wv0.z = pk2(f1.x,f1.y); wv0.w = pk2(f1.z,f1.w);
            wv1.x = pk2(f2.x,f2.y); wv1.y = pk2(f2.z,f2.w);
            wv1.z = pk2(f3.x,f3.y); wv1.w = pk2(f3.z,f3.w);
            *(uint4*)a_w0 = wv0;
            *(uint4*)a_w1 = wv1;
        }
        __syncthreads();
        #pragma unroll
        for (int ks = 0; ks < 2; ++ks) {
            const int kc = ks * 4 + koct;
            bf16x8 af[4], bfr[4];
            #pragma unroll
            for (int mi = 0; mi < 4; ++mi) {
                int r = mi * 16 + l15;
                af[mi] = *(const bf16x8*)(asmem + r * 128 + ((kc * 16) ^ ((r & 7) << 4)));
            }
            #pragma unroll
            for (int ni = 0; ni < 4; ++ni) {
                int c = w * 64 + ni * 16 + l15;
                bfr[ni] = *(const bf16x8*)(bsmem + c * 128 + ((kc * 16) ^ ((c & 7) << 4)));
            }
            #pragma unroll
            for (int mi = 0; mi < 4; ++mi)
                #pragma unroll
                for (int ni = 0; ni < 4; ++ni)
                    acc[mi][ni] = __builtin_amdgcn_mfma_f32_16x16x32_bf16(
                        af[mi], bfr[ni], acc[mi][ni], 0, 0, 0);
        }
        __syncthreads();
    }

    #pragma unroll
    for (int mi = 0; mi < 4; ++mi) {
        int rbase = i0 + mi * 16 + (lane >> 4) * 4;
        #pragma unroll
        for (int j = 0; j < 4; ++j) {
            int grow = rbase + j;
            if (grow < M) {
                #pragma unroll
                for (int ni = 0; ni < 4; ++ni) {
                    int gcol = o0 + w * 64 + ni * 16 + l15;
                    float v = acc[mi][ni][j] + bias_v[ni];
                    if (OUT_BF16)
                        ((unsigned short*)outp)[(size_t)grow * N + gcol] =
                            __bfloat16_as_ushort(__float2bfloat16(v));
                    else
                        ((float*)outp)[(size_t)grow * N + gcol] = v;
                }
            }
        }
    }
}

// ---------------- fused: softmax + locations + 4-corner gather (R10/R11-proven) ----------------
// Scoreboard: this exact variant ≈26-30us (R10/R11, inferred); paired-row+shfl=52
// (R12); unroll-8=53 (R13, VGPR collapsed); 512-thr half-wave=66 (R14). Verbatim
// revert to the best-known version: 256 thr, unroll 4, branchy 4-corner gather.
__global__ __launch_bounds__(256)
void fused_sample(const float* __restrict__ logits,        // (4000, 512) m*64+p
                  const float* __restrict__ ref_pts,       // (4,1000,2)
                  const unsigned short* __restrict__ value,// bf16 (4, 19822, 256)
                  const float* __restrict__ consts,        // 4*48
                  float* __restrict__ attn_out) {          // (4000, 256)
    int b = blockIdx.x;
    int n = b / LQ;
    int q = b - n * LQ;
    int tid = threadIdx.x;

    __shared__ float s_attn[512];
    __shared__ float s_loc[16][2];
    __shared__ int   s_idx[64][4];
    __shared__ float s_w[64][4];
    __shared__ float4 s_part[4][64];

    s_attn[tid]       = logits[(size_t)b * 512 + tid];
    s_attn[tid + 256] = logits[(size_t)b * 512 + tid + 256];
    __syncthreads();

    {   // softmax per head
        int wave = tid >> 6, lane = tid & 63;
        for (int h = wave; h < NHEAD; h += 4) {
            float v = s_attn[h * 64 + lane];
            float mx = v;
            #pragma unroll
            for (int off = 32; off; off >>= 1) mx = fmaxf(mx, __shfl_xor(mx, off, 64));
            float e = expf(v - mx);
            float sm = e;
            #pragma unroll
            for (int off = 32; off; off >>= 1) sm += __shfl_xor(sm, off, 64);
            s_attn[h * 64 + lane] = e / sm;
        }
    }

    if (tid < 16) {   // 16 distinct sampling locations (shared by all 4 levels)
        const float* C = consts + n * 48;
        float rx = ref_pts[((size_t)n * LQ + q) * 2 + 0];
        float ry = ref_pts[((size_t)n * LQ + q) * 2 + 1];
        float dx = rx - C[4], dy = ry - C[5];
        float ox = (C[0]*dx + C[1]*dy) * IMGF;
        float oy = (C[2]*dx + C[3]*dy) * IMGF;
        float u0 = ox - C[15], u1 = oy - C[16], u2 = 1.0f - C[17];
        float r0 = C[6]*u0  + C[7]*u1  + C[8]*u2;
        float r1 = C[9]*u0  + C[10]*u1 + C[11]*u2;
        float r2 = C[12]*u0 + C[13]*u1 + C[14]*u2;
        float y0 = C[18]*r0 + C[19]*r1 + C[20]*r2 + C[21];
        float y1 = C[22]*r0 + C[23]*r1 + C[24]*r2 + C[25];
        float y2 = C[26]*r0 + C[27]*r1 + C[28]*r2 + C[29];
        float inv = 1.0f/(y2 + 1e-8f);
        float prx = y0*inv, pry = y1*inv;
        float ts0 = C[30], ts1 = C[31];
        float msx = (prx - ts0) / IMGF, msy = (pry - ts1) / IMGF;
        int j = tid;
        float xsj = IMGF * ((float)j / 15.0f);
        float lx = (ts0 + msx * xsj) / IMGF;
        float ly = (ts1 + msy * xsj) / IMGF;
        float Lx = C[32]*lx + C[33]*ly + C[34];
        float Ly = C[35]*lx + C[36]*ly + C[37];
        s_loc[j][0] = fminf(fmaxf(Lx, 0.0f), 1.0f);
        s_loc[j][1] = fminf(fmaxf(Ly, 0.0f), 1.0f);
    }
    __syncthreads();

    if (tid < 64) {   // bilinear metadata per point
        int p = tid, lev = p >> 4, j = p & 15;
        int H = c_LH[lev], W = c_LW[lev], st = c_LST[lev];
        float gx = s_loc[j][0] * (float)W - 0.5f;
        float gy = s_loc[j][1] * (float)H - 0.5f;
        float x0f = floorf(gx), y0f = floorf(gy);
        float wx = gx - x0f, wy = gy - y0f;
        int x0 = (int)x0f, y0 = (int)y0f;
        int x1 = x0 + 1, y1 = y0 + 1;
        bool vx0 = (x0 >= 0) & (x0 < W), vx1 = (x1 >= 0) & (x1 < W);
        bool vy0 = (y0 >= 0) & (y0 < H), vy1 = (y1 >= 0) & (y1 < H);
        s_idx[p][0] = (vx0 & vy0) ? st + y0 * W + x0 : -1;  s_w[p][0] = (1.f-wx)*(1.f-wy);
        s_idx[p][1] = (vx1 & vy0) ? st + y0 * W + x1 : -1;  s_w[p][1] = wx*(1.f-wy);
        s_idx[p][2] = (vx0 & vy1) ? st + y1 * W + x0 : -1;  s_w[p][2] = (1.f-wx)*wy;
        s_idx[p][3] = (vx1 & vy1) ? st + y1 * W + x1 : -1;  s_w[p][3] = wx*wy;
    }
    __syncthreads();

    // gather + weighted sum; value batch is swap_pairs -> n^1
    int wv = tid >> 6, lane = tid & 63;
    const unsigned short* vbase = value + (size_t)(n ^ 1) * STOT * DMODEL + lane * 4;
    int m = lane >> 3;   // head of channel lane*4
    float a0 = 0.f, a1 = 0.f, a2 = 0.f, a3 = 0.f;
    #pragma unroll 4
    for (int j = 0; j < 16; ++j) {
        int p = wv * 16 + j;
        float wa = s_attn[m * 64 + p];
        float s0 = 0.f, s1 = 0.f, s2 = 0.f, s3 = 0.f;
        #pragma unroll
        for (int cc = 0; cc < 4; ++cc) {
            int idx = s_idx[p][cc];
            if (idx >= 0) {
                ushort4 vv = *(const ushort4*)(vbase + (size_t)idx * DMODEL);
                float wgt = s_w[p][cc];
                s0 += wgt * bf2f(vv.x);
                s1 += wgt * bf2f(vv.y);
                s2 += wgt * bf2f(vv.z);
                s3 += wgt * bf2f(vv.w);
            }
        }
        a0 += wa * s0; a1 += wa * s1; a2 += wa * s2; a3 += wa * s3;
    }
    s_part[wv][lane] = make_float4(a0, a1, a2, a3);
    __syncthreads();

    const float* sp = (const float*)s_part;
    float r = sp[tid] + sp[256 + tid] + sp[512 + tid] + sp[768 + tid];
    attn_out[(size_t)b * DMODEL + tid] = r;
}

// ---------------- launch ----------------
extern "C" void kernel_launch(void* const* d_in, const int* in_sizes, int n_in,
                              void* d_out, int out_size, void* d_ws, size_t ws_size,
                              hipStream_t stream) {
    const float* query         = (const float*)d_in[0];
    const float* input_flatten = (const float*)d_in[1];
    const float* ref_pts       = (const float*)d_in[2];
    const float* p_pfws        = (const float*)d_in[3];
    const float* pt            = (const float*)d_in[4];
    const float* W_val         = (const float*)d_in[5];
    const float* b_val         = (const float*)d_in[6];
    const float* W_attn        = (const float*)d_in[7];
    const float* b_attn        = (const float*)d_in[8];
    const float* W_out         = (const float*)d_in[9];
    const float* b_out         = (const float*)d_in[10];
    float* out = (float*)d_out;

    const int M = NB * STOT;                                   // 79288
    const size_t value_bytes  = (size_t)M * DMODEL * 2;        // bf16
    const size_t logits_bytes = (size_t)NB * LQ * 512 * 4;
    const size_t attn_bytes   = (size_t)NB * LQ * DMODEL * 4;
    const size_t consts_bytes = NB * 48 * 4;
    const size_t wv_bytes     = (size_t)DMODEL * DMODEL * 2;
    const size_t wa_bytes     = (size_t)512 * DMODEL * 2;
    const size_t wo_bytes     = (size_t)DMODEL * DMODEL * 2;
    const size_t need = value_bytes + logits_bytes + attn_bytes + consts_bytes
                      + wv_bytes + wa_bytes + wo_bytes;
    if (ws_size < need) return;

    char* p = (char*)d_ws;
    unsigned short* value = (unsigned short*)p;  p += value_bytes;
    float* logits   = (float*)p;                 p += logits_bytes;
    float* attn_out = (float*)p;                 p += attn_bytes;
    float* consts   = (float*)p;                 p += consts_bytes;
    unsigned short* wb_val  = (unsigned short*)p; p += wv_bytes;
    unsigned short* wb_attn = (unsigned short*)p; p += wa_bytes;
    unsigned short* wb_out  = (unsigned short*)p; p += wo_bytes;

    prep<<<257, 256, 0, stream>>>(W_val, W_attn, W_out, wb_val, wb_attn, wb_out,
                                  p_pfws, pt, consts);

    {   // value = bf16(input_flatten @ W_val.T + b_val): reg-B rows pipeline
        const int T = (M + 31) / 32;               // 2478 row tiles
        const int CHUNK = 5;
        const int blocks = (T + CHUNK - 1) / CHUNK; // 496
        gemm_val_regB<<<blocks, 256, 0, stream>>>(input_flatten, wb_val, b_val,
                                                  value, M, T, CHUNK);
    }
    {   // logits = query @ W_attn.T + b_attn   (N=512 -> grid.y=2)
        dim3 g((NB * LQ + 63) / 64, 2);
        gemm64<false><<<g, 256, 0, stream>>>(query, wb_attn, b_attn, logits, NB * LQ, 512);
    }
    fused_sample<<<NB * LQ, 256, 0, stream>>>(logits, ref_pts, value, consts, attn_out);
    {   // out = attn_out @ W_out.T + b_out
        dim3 g((NB * LQ + 63) / 64, 1);
        gemm64<false><<<g, 256, 0, stream>>>(attn_out, wb_out, b_out, out, NB * LQ, DMODEL);
    }
}